// Round 1
// baseline (608.116 us; speedup 1.0000x reference)
//
#include <hip/hip_runtime.h>

// SelMul: out[b][rs(i) + (j-i)] = x[b][i] * x[b][j], i<=j, row-major upper-tri.
// B=256, N=1024, TRI=524800 -> 537 MB fp32 output, 1 MB input: pure write-stream.
//
// Round-2 analysis: flat-float4 kernel ran ~263 us (~2.0 TB/s) while the harness's
// own 2.15 GB poison fill sustains 6.3 TB/s -- the kernel was VALU/TA-bound on the
// per-float4 triangular inversion (sqrt + magic div + branches) and 5 scalar L1
// gathers per 16B store. This version reframes the op as a scaled contiguous copy:
//   row i  =  x[b][i] * x[b][i..N)   written at rowstart(i).
// Pair row i with row N-1-i (uniform ~1025 elems/pair). Grid = 256 b x 8 chunks
// (2048 blocks, 8/CU, full 32-wave occupancy). Each block stages its 4 KB x-row
// in LDS once, then does block-wide float4 scaled copies; row metadata is
// block-uniform -> SALU. Scalar head/tail handles rowstart mod-4 store alignment.

#define N 1024
#define TRI (N * (N + 1) / 2)      // 524800
#define TPB 256
#define PAIRS 64                   // row-pairs per block
#define CHUNKS (N / 2 / PAIRS)     // 8 chunks of pairs per batch row
#define NBLOCKS (256 * CHUNKS)     // 2048 blocks

__device__ __forceinline__ void row_copy(float* __restrict__ outb,
                                         const float* __restrict__ sx,
                                         int i, int t) {
    const int L = N - i;                         // row length (uniform)
    const int rs = (i * (2 * N + 1 - i)) >> 1;   // rowstart(i) (uniform)
    const float xi = sx[i];                      // uniform LDS broadcast
    float* const dst = outb + rs;

    int h = (4 - (rs & 3)) & 3;                  // scalar head to reach 16B align
    h = (h < L) ? h : L;
    if (t < h) dst[t] = xi * sx[i + t];

    const int nb4 = (L - h) >> 2;                // aligned float4 body
    for (int m = t; m < nb4; m += TPB) {
        const int k = h + (m << 2);
        const float* __restrict__ s = sx + i + k;
        float4 v;
        v.x = xi * s[0];
        v.y = xi * s[1];
        v.z = xi * s[2];
        v.w = xi * s[3];
        *reinterpret_cast<float4*>(dst + k) = v; // coalesced 16B/lane store
    }

    const int tail = (L - h) & 3;                // scalar tail
    if (t < tail) {
        const int k = h + (nb4 << 2) + t;
        dst[k] = xi * sx[i + k];
    }
}

__global__ __launch_bounds__(TPB) void selmul_kernel(const float* __restrict__ x,
                                                     float* __restrict__ out) {
    __shared__ float sx[N];
    const int b = blockIdx.x / CHUNKS;
    const int c = blockIdx.x % CHUNKS;
    const int t = threadIdx.x;

    // Stage the 4 KB x-row: 256 threads x one float4 each.
    reinterpret_cast<float4*>(sx)[t] =
        reinterpret_cast<const float4*>(x + b * N)[t];
    __syncthreads();

    float* const outb = out + (size_t)b * TRI;
    const int i0 = c * PAIRS;
#pragma unroll 1
    for (int p = 0; p < PAIRS; ++p) {
        const int i = i0 + p;
        row_copy(outb, sx, i, t);               // long row of the pair
        row_copy(outb, sx, (N - 1) - i, t);     // short partner row
    }
}

extern "C" void kernel_launch(void* const* d_in, const int* in_sizes, int n_in,
                              void* d_out, int out_size, void* d_ws, size_t ws_size,
                              hipStream_t stream) {
    const float* x = (const float*)d_in[0];
    float* out = (float*)d_out;
    selmul_kernel<<<NBLOCKS, TPB, 0, stream>>>(x, out);
}

// Round 3
// 576.312 us; speedup vs baseline: 1.0552x; 1.0552x over previous
//
#include <hip/hip_runtime.h>

// SelMul: out[b][rs(i)+(j-i)] = x[b][i]*x[b][j], i<=j, row-major upper-tri.
// B=256, N=1024, TRI=524800 -> 537 MB fp32 write-stream, 1 MB input.
//
// r0 (flat+sqrt) and r1 (LDS row-pair) both ran ~260 us (~2.05 TB/s) vs the
// harness's own 2.15 GB fill at 6.3 TB/s. Common factor: every 16B store was
// serially coupled to a conflicted read (r0: five stride-4 L1 gathers + sqrt
// chain; r1: 4x stride-4 ds_read_b32 = 8-way bank conflict + lgkmcnt wait,
// re-paid per branchy row_copy call). This version makes the read side as
// clean as the write side:
//   - wave owns row-pair (i, 1023-i): exactly 1025 floats/pair, 16 pairs/wave
//   - source read as TWO aligned coalesced dwordx4 loads per 1 KB store;
//     row-uniform misalignment d=(i+h)&3 resolved by a scalar 4-way switch
//   - store alignment: <=3-lane head + <=7-lane tail, once per ROW
//   - no LDS, no sqrt, no div, no per-float4 branches
//   - nontemporal body stores via clang ext_vector float4 (HIP float4 struct
//     is rejected by __builtin_nontemporal_store -- r2 compile fix)

#define N 1024
#define TRI (N * (N + 1) / 2)          // 524800
#define TPB 256
#define NBLOCKS 2048
#define NWAVES (NBLOCKS * (TPB / 64))  // 8192
#define NJOBS (256 * 512)              // (b, pair) jobs
#define JOBS_PER_WAVE (NJOBS / NWAVES) // 16

typedef float vf4 __attribute__((ext_vector_type(4)));

__device__ __forceinline__ void do_row(const float* __restrict__ xrow,
                                       float* __restrict__ outb,
                                       int i, int lane) {
    const int L = N - i;                          // row length (wave-uniform)
    const int rs = (i * (2 * N + 1 - i)) >> 1;    // rowstart(i)
    const float xi = xrow[i];                     // uniform-address L1 broadcast
    float* const dst = outb + rs;
    const float* const src = xrow + i;

    int h = (-rs) & 3;                            // head to 16B-align dst
    h = h < L ? h : L;
    const int d = (i + h) & 3;                    // src misalignment vs dst
    const int base = (i + h) - d;                 // aligned src word index
    int nb4 = (L - h) >> 2;
    if (d && nb4) --nb4;                          // last f4 -> tail (keeps b-load in-row)

    if (lane < h) dst[lane] = xi * src[lane];     // predicated head (<=3 lanes)

    const vf4* __restrict__ s4 = reinterpret_cast<const vf4*>(xrow + base);
    vf4* const d4 = reinterpret_cast<vf4*>(dst + h);

    switch (d) {                                  // wave-uniform scalar branch
    case 0:
        for (int m = lane; m < nb4; m += 64) {
            const vf4 a = s4[m];
            __builtin_nontemporal_store(xi * a, &d4[m]);
        }
        break;
    case 1:
        for (int m = lane; m < nb4; m += 64) {
            const vf4 a = s4[m], b = s4[m + 1];
            vf4 o; o.x = a.y; o.y = a.z; o.z = a.w; o.w = b.x;
            __builtin_nontemporal_store(xi * o, &d4[m]);
        }
        break;
    case 2:
        for (int m = lane; m < nb4; m += 64) {
            const vf4 a = s4[m], b = s4[m + 1];
            vf4 o; o.x = a.z; o.y = a.w; o.z = b.x; o.w = b.y;
            __builtin_nontemporal_store(xi * o, &d4[m]);
        }
        break;
    default:
        for (int m = lane; m < nb4; m += 64) {
            const vf4 a = s4[m], b = s4[m + 1];
            vf4 o; o.x = a.w; o.y = b.x; o.z = b.y; o.w = b.z;
            __builtin_nontemporal_store(xi * o, &d4[m]);
        }
        break;
    }

    const int done = h + (nb4 << 2);              // tail (<=7 lanes)
    const int k = done + lane;
    if (k < L) dst[k] = xi * src[k];
}

__global__ __launch_bounds__(TPB) void selmul_kernel(const float* __restrict__ x,
                                                     float* __restrict__ out) {
    const int w = (blockIdx.x * TPB + threadIdx.x) >> 6;  // global wave id
    const int lane = threadIdx.x & 63;
#pragma unroll 1
    for (int k = 0; k < JOBS_PER_WAVE; ++k) {
        const int q = w + k * NWAVES;             // job id, bijective over [0, NJOBS)
        const int b = q >> 9;                     // 512 pairs per batch row
        const int ip = q & 511;
        const float* xrow = x + b * N;
        float* outb = out + (size_t)b * TRI;
        do_row(xrow, outb, ip, lane);             // long row of the pair
        do_row(xrow, outb, (N - 1) - ip, lane);   // short partner row
    }
}

extern "C" void kernel_launch(void* const* d_in, const int* in_sizes, int n_in,
                              void* d_out, int out_size, void* d_ws, size_t ws_size,
                              hipStream_t stream) {
    const float* x = (const float*)d_in[0];
    float* out = (float*)d_out;
    selmul_kernel<<<NBLOCKS, TPB, 0, stream>>>(x, out);
}

// Round 4
// 548.722 us; speedup vs baseline: 1.1082x; 1.0503x over previous
//
#include <hip/hip_runtime.h>

// SelMul: out[b][rs(i)+(j-i)] = x[b][i]*x[b][j], i<=j, row-major upper-tri.
// B=256, N=1024, TRI=524800 -> 537 MB fp32 write-stream, 1 MB input.
//
// r4 theory: r0/r3 (global-read variants) pinned at 2.0-2.4 TB/s because loads
// and stores share the in-order vmcnt queue: the s_waitcnt before consuming a
// row's loads serializes behind the previous row's outstanding stores (~1000
// cyc/store observed). r1 (LDS) avoided that but died on 8-way ds_read_b32
// bank conflicts + block-wide branchy per-row overhead.
// This version: hot loop's ONLY wait is lgkmcnt.
//   - 4 shift-copies of the 4 KB x-row in LDS: sx[c][t] = x[t+c]. Row src
//     misalignment d becomes ONE aligned ds_read_b128 from copy d
//     (contiguous lanes -> conflict-free). 16 KB/block, 8 blocks/CU = 128 KB.
//   - hot loop per 1 KB: ds_read_b128 -> 4x v_mul -> global_store_dwordx4.
//     Stores only waited for register recycle (shallow vmcnt, drains at BW).
//   - plain stores (fill kernel proves 6.1 TB/s with plain stores; nt dropped)
//   - wave owns row-pairs (i, 1023-i); all row metadata wave-uniform (SALU);
//     head <=3 lanes, tail <=3 lanes.

#define N 1024
#define TRI (N * (N + 1) / 2)     // 524800
#define TPB 256
#define CHUNKS 8                  // pair-chunks per batch row
#define NBLOCKS (256 * CHUNKS)    // 2048 blocks -> 8/CU, 32 waves/CU
#define PAIRS_PER_WAVE 16         // 512 pairs / (CHUNKS * 4 waves)

typedef float vf4 __attribute__((ext_vector_type(4)));

__global__ __launch_bounds__(TPB) void selmul_kernel(const float* __restrict__ x,
                                                     float* __restrict__ out) {
    __shared__ float sx[4][N];    // sx[c][t] = xrow[t+c]

    const int b = blockIdx.x / CHUNKS;
    const int chunk = blockIdx.x % CHUNKS;
    const int tid = threadIdx.x;
    const int wv = tid >> 6;
    const int lane = tid & 63;

    const float* __restrict__ xrow = x + b * N;

    // Stage 4 shifted copies (vectorized read; row is L1-resident after pass 0).
#pragma unroll
    for (int c = 0; c < 4; ++c) {
        for (int t = tid; t < N; t += TPB) {
            const int g = t + c;
            sx[c][t] = (g < N) ? xrow[g] : 0.0f;
        }
    }
    __syncthreads();

    float* const outb = out + (size_t)b * TRI;
    const int ip0 = chunk * 64 + wv * PAIRS_PER_WAVE;

#pragma unroll 1
    for (int p = 0; p < PAIRS_PER_WAVE; ++p) {
        const int ipair = ip0 + p;
#pragma unroll
        for (int half = 0; half < 2; ++half) {
            const int i = half ? (N - 1) - ipair : ipair;   // long row, then short
            const int L = N - i;                            // wave-uniform
            const int rs = (i * (2 * N + 1 - i)) >> 1;      // rowstart(i)
            const float xi = sx[0][i];                      // uniform broadcast
            float* const dst = outb + rs;

            int h = (-rs) & 3;                              // head to 16B-align dst
            h = h < L ? h : L;
            const int s = i + h;
            const int d = s & 3;                            // shift-copy select
            const int nb4 = (L - h) >> 2;

            if (lane < h) dst[lane] = xi * sx[0][i + lane]; // head (<=3 lanes)

            const vf4* __restrict__ lsrc =
                reinterpret_cast<const vf4*>(&sx[d][s - d]);
            vf4* const d4 = reinterpret_cast<vf4*>(dst + h);

            for (int m = lane; m < nb4; m += 64) {          // 1 KB/wave-iter
                const vf4 a = lsrc[m];                      // aligned ds_read_b128
                d4[m] = xi * a;                             // global_store_dwordx4
            }

            const int done = h + (nb4 << 2);                // tail (<=3 lanes)
            const int k = done + lane;
            if (k < L) dst[k] = xi * sx[0][i + k];
        }
    }
}

extern "C" void kernel_launch(void* const* d_in, const int* in_sizes, int n_in,
                              void* d_out, int out_size, void* d_ws, size_t ws_size,
                              hipStream_t stream) {
    const float* x = (const float*)d_in[0];
    float* out = (float*)d_out;
    selmul_kernel<<<NBLOCKS, TPB, 0, stream>>>(x, out);
}